// Round 4
// baseline (200.684 us; speedup 1.0000x reference)
//
#include <hip/hip_runtime.h>

#define HIDDEN 512
#define HEADS 8
#define DK 64
#define S_ 1024
#define NEGV -1000000000.0f

typedef _Float16 half8 __attribute__((ext_vector_type(8)));
typedef _Float16 half4 __attribute__((ext_vector_type(4)));
typedef _Float16 half2_t __attribute__((ext_vector_type(2)));
typedef float f32x4 __attribute__((ext_vector_type(4)));
typedef float f32x2 __attribute__((ext_vector_type(2)));
typedef int i32x4 __attribute__((ext_vector_type(4)));

// ---------------- fp32 -> fp16 converters ----------------
__global__ __launch_bounds__(256) void cvt3(const float* __restrict__ a0,
                                            const float* __restrict__ a1,
                                            const float* __restrict__ a2,
                                            _Float16* o0, _Float16* o1, _Float16* o2) {
  const float* src = blockIdx.y == 0 ? a0 : (blockIdx.y == 1 ? a1 : a2);
  _Float16* dst = blockIdx.y == 0 ? o0 : (blockIdx.y == 1 ? o1 : o2);
  int i = (blockIdx.x * 256 + threadIdx.x) * 4;
  float4 v = *(const float4*)(src + i);
  half4 h = {(_Float16)v.x, (_Float16)v.y, (_Float16)v.z, (_Float16)v.w};
  *(half4*)(dst + i) = h;
}

__global__ __launch_bounds__(256) void cvt4(const float* __restrict__ a0,
                                            const float* __restrict__ a1,
                                            const float* __restrict__ a2,
                                            const float* __restrict__ a3,
                                            _Float16* o0, _Float16* o1, _Float16* o2, _Float16* o3) {
  const float* src = blockIdx.y == 0 ? a0 : (blockIdx.y == 1 ? a1 : (blockIdx.y == 2 ? a2 : a3));
  _Float16* dst = blockIdx.y == 0 ? o0 : (blockIdx.y == 1 ? o1 : (blockIdx.y == 2 ? o2 : o3));
  int i = (blockIdx.x * 256 + threadIdx.x) * 4;
  float4 v = *(const float4*)(src + i);
  half4 h = {(_Float16)v.x, (_Float16)v.y, (_Float16)v.z, (_Float16)v.w};
  *(half4*)(dst + i) = h;
}

// ---------------- fused QKV projection ----------------
__global__ __launch_bounds__(256) void proj_qkv(
    const _Float16* __restrict__ q16, const _Float16* __restrict__ k16,
    const _Float16* __restrict__ v16,
    const _Float16* __restrict__ wq, const _Float16* __restrict__ wk,
    const _Float16* __restrict__ wv,
    const float* __restrict__ bq, const float* __restrict__ bk,
    const float* __restrict__ bv,
    _Float16* __restrict__ qh, _Float16* __restrict__ kh, _Float16* __restrict__ vt) {
  int m0 = blockIdx.x * 64;
  int nb = blockIdx.y;
  int which = nb >> 3;
  int n0 = (nb & 7) * 64;
  const _Float16* X = which == 0 ? q16 : (which == 1 ? k16 : v16);
  const _Float16* W = which == 0 ? wq : (which == 1 ? wk : wv);
  const float* bias = which == 0 ? bq : (which == 1 ? bk : bv);

  int tid = threadIdx.x;
  int wave = tid >> 6, lane = tid & 63;
  int r16 = lane & 15, quad = lane >> 4;

  const _Float16* Xp = X + (m0 + wave * 16 + r16) * HIDDEN + quad * 8;
  const _Float16* Wp = W + (n0 + r16) * HIDDEN + quad * 8;

  f32x4 acc[4] = {};
  for (int k0 = 0; k0 < HIDDEN; k0 += 32) {
    half8 a = *(const half8*)(Xp + k0);
#pragma unroll
    for (int nt = 0; nt < 4; nt++) {
      half8 bfr = *(const half8*)(Wp + nt * 16 * HIDDEN + k0);
      acc[nt] = __builtin_amdgcn_mfma_f32_16x16x32_f16(a, bfr, acc[nt], 0, 0, 0);
    }
  }

  __shared__ _Float16 T[64][72];

  if (which < 2) {
    _Float16* OUT = which == 0 ? qh : kh;
    float scale = which == 0 ? 0.125f : 1.0f;  // DK^-0.5 = 1/8
#pragma unroll
    for (int nt = 0; nt < 4; nt++) {
      int gcol = n0 + nt * 16 + r16;
      float bv_ = bias[gcol];
      int h = gcol >> 6, d = gcol & 63;
#pragma unroll
      for (int r = 0; r < 4; r++) {
        int grow = m0 + wave * 16 + quad * 4 + r;
        int bb = grow >> 10, s = grow & 1023;
        float val = (acc[nt][r] + bv_) * scale;
        OUT[((bb * HEADS + h) * S_ + s) * DK + d] = (_Float16)val;
      }
    }
  } else {
    // V: transpose 64x64 tile via LDS, write vt[b][h][d][s]
#pragma unroll
    for (int nt = 0; nt < 4; nt++) {
      int lc = nt * 16 + r16;
      float bv_ = bias[n0 + lc];
#pragma unroll
      for (int r = 0; r < 4; r++) {
        int lr = wave * 16 + quad * 4 + r;
        T[lr][lc] = (_Float16)(acc[nt][r] + bv_);
      }
    }
    __syncthreads();
    int dl = tid >> 2;
    int s4 = (tid & 3) * 16;
    _Float16 tmp[16];
#pragma unroll
    for (int i = 0; i < 16; i++) tmp[i] = T[s4 + i][dl];
    int h = n0 >> 6;
    int bb = m0 >> 10;
    int s0 = m0 & 1023;
    _Float16* p = vt + ((bb * HEADS + h) * DK + dl) * S_ + s0 + s4;
    *(half8*)(p) = *(half8*)(tmp);
    *(half8*)(p + 8) = *(half8*)(tmp + 8);
  }
}

// ---------------- attention v4: register-double-buffered HBM prefetch ----------------
// grid (S/64, B*H); 8 waves. Waves 0-3: kv [0,512), 4-7: [512,1024).
// Per wave 16 q-rows. bias/gmask/subsq for step i+1 are issued at top of step i
// into the alternate register buffer -> HBM loads stay in flight across compute.
struct Buf {
  f32x4 bi0, bi1, sq0, sq1;
  i32x4 gm0, gm1;
};

__global__ __launch_bounds__(512, 4) void attn4(
    const _Float16* __restrict__ qh, const _Float16* __restrict__ kh,
    const _Float16* __restrict__ vt,
    const float* __restrict__ attn_bias, const int* __restrict__ gmask,
    const float* __restrict__ subsq, _Float16* __restrict__ ao) {
  int bh = blockIdx.y;
  int b = bh >> 3, h = bh & 7;
  int tid = threadIdx.x;
  int wave = tid >> 6, lane = tid & 63;
  int col = lane & 15, quad = lane >> 4;
  int qw = wave & 3, zz = wave >> 2;
  int q = blockIdx.x * 64 + qw * 16 + col;

  __shared__ unsigned P2[8][16][20];
  __shared__ float CACC[4][16][66];
  __shared__ float CML[4][16][2];

  const _Float16* Q = qh + ((size_t)bh * S_ + q) * DK;
  const _Float16* K = kh + (size_t)bh * S_ * DK;
  const _Float16* V = vt + (size_t)bh * DK * S_;
  const float* BI = attn_bias + ((size_t)bh * S_ + q) * S_;
  const int* GM = gmask + ((size_t)b * S_ + q) * S_;
  const float* SQ = subsq + ((size_t)b * S_ + q) * S_;

  half8 qf0 = *(const half8*)(Q + quad * 8);
  half8 qf1 = *(const half8*)(Q + 32 + quad * 8);

  f32x4 acc[4] = {};  // out^T: acc[nt][r] = out[d = nt*16+quad*4+r][q]
  float m_r = -1e38f, l_r = 0.0f;

  int kv0 = zz * 512;

  Buf bufA, bufB;
  // prologue: step-0 operands
  {
    int kc = kv0;
    bufA.bi0 = *(const f32x4*)(BI + kc + quad * 4);
    bufA.bi1 = *(const f32x4*)(BI + kc + 16 + quad * 4);
    bufA.gm0 = *(const i32x4*)(GM + kc + quad * 4);
    bufA.gm1 = *(const i32x4*)(GM + kc + 16 + quad * 4);
    bufA.sq0 = *(const f32x4*)(SQ + kc + quad * 4);
    bufA.sq1 = *(const f32x4*)(SQ + kc + 16 + quad * 4);
  }

  auto body = [&](Buf& R, Buf& W, int kc, int kcn) {
    // --- issue next step's HBM loads first (consumed next body) ---
    W.bi0 = *(const f32x4*)(BI + kcn + quad * 4);
    W.bi1 = *(const f32x4*)(BI + kcn + 16 + quad * 4);
    W.gm0 = *(const i32x4*)(GM + kcn + quad * 4);
    W.gm1 = *(const i32x4*)(GM + kcn + 16 + quad * 4);
    W.sq0 = *(const f32x4*)(SQ + kcn + quad * 4);
    W.sq1 = *(const f32x4*)(SQ + kcn + 16 + quad * 4);

    // --- K/V loads for current step (L2-resident mostly) ---
    const _Float16* Kp0 = K + (size_t)(kc + col) * DK + quad * 8;
    const _Float16* Kp1 = K + (size_t)(kc + 16 + col) * DK + quad * 8;
    half8 kf00 = *(const half8*)(Kp0);
    half8 kf01 = *(const half8*)(Kp0 + 32);
    half8 kf10 = *(const half8*)(Kp1);
    half8 kf11 = *(const half8*)(Kp1 + 32);

    const _Float16* Vb = V + kc + quad * 8;
    half8 vf0 = *(const half8*)(Vb + (0 * 16 + col) * S_);
    half8 vf1 = *(const half8*)(Vb + (1 * 16 + col) * S_);
    half8 vf2 = *(const half8*)(Vb + (2 * 16 + col) * S_);
    half8 vf3 = *(const half8*)(Vb + (3 * 16 + col) * S_);

    // --- QK^T swapped: S^T[k][q] ---
    f32x4 s0 = {}, s1 = {};
    s0 = __builtin_amdgcn_mfma_f32_16x16x32_f16(kf00, qf0, s0, 0, 0, 0);
    s0 = __builtin_amdgcn_mfma_f32_16x16x32_f16(kf01, qf1, s0, 0, 0, 0);
    s1 = __builtin_amdgcn_mfma_f32_16x16x32_f16(kf10, qf0, s1, 0, 0, 0);
    s1 = __builtin_amdgcn_mfma_f32_16x16x32_f16(kf11, qf1, s1, 0, 0, 0);

    float x0[4], x1[4];
#pragma unroll
    for (int r = 0; r < 4; r++) {
      x0[r] = (R.gm0[r] == 0) ? NEGV : (s0[r] + R.bi0[r] + R.sq0[r]);
      x1[r] = (R.gm1[r] == 0) ? NEGV : (s1[r] + R.bi1[r] + R.sq1[r]);
    }

    float mx = fmaxf(fmaxf(fmaxf(x0[0], x0[1]), fmaxf(x0[2], x0[3])),
                     fmaxf(fmaxf(x1[0], x1[1]), fmaxf(x1[2], x1[3])));
    mx = fmaxf(mx, __shfl_xor(mx, 16));
    mx = fmaxf(mx, __shfl_xor(mx, 32));
    float mnew = fmaxf(m_r, mx);
    float f = __expf(m_r - mnew);
    float p0[4], p1[4];
    float ps = 0.0f;
#pragma unroll
    for (int r = 0; r < 4; r++) {
      p0[r] = __expf(x0[r] - mnew);
      p1[r] = __expf(x1[r] - mnew);
      ps += p0[r] + p1[r];
    }
    ps += __shfl_xor(ps, 16);
    ps += __shfl_xor(ps, 32);
    l_r = l_r * f + ps;
    m_r = mnew;
#pragma unroll
    for (int nt = 0; nt < 4; nt++) acc[nt] *= f;

    half2_t c0 = {(_Float16)p0[0], (_Float16)p0[1]};
    half2_t c1 = {(_Float16)p0[2], (_Float16)p0[3]};
    half2_t c2 = {(_Float16)p1[0], (_Float16)p1[1]};
    half2_t c3 = {(_Float16)p1[2], (_Float16)p1[3]};
    P2[wave][col][quad * 2 + 0] = __builtin_bit_cast(unsigned, c0);
    P2[wave][col][quad * 2 + 1] = __builtin_bit_cast(unsigned, c1);
    P2[wave][col][8 + quad * 2 + 0] = __builtin_bit_cast(unsigned, c2);
    P2[wave][col][8 + quad * 2 + 1] = __builtin_bit_cast(unsigned, c3);

    half8 pf = *(const half8*)&P2[wave][col][quad * 4];

    acc[0] = __builtin_amdgcn_mfma_f32_16x16x32_f16(vf0, pf, acc[0], 0, 0, 0);
    acc[1] = __builtin_amdgcn_mfma_f32_16x16x32_f16(vf1, pf, acc[1], 0, 0, 0);
    acc[2] = __builtin_amdgcn_mfma_f32_16x16x32_f16(vf2, pf, acc[2], 0, 0, 0);
    acc[3] = __builtin_amdgcn_mfma_f32_16x16x32_f16(vf3, pf, acc[3], 0, 0, 0);
  };

#pragma unroll 2
  for (int ii = 0; ii < 8; ii++) {
    int kc = kv0 + ii * 64;
    int kcn2 = (ii == 7) ? kv0 : kc + 64;  // wrap: last prefetch unused
    body(bufA, bufB, kc, kc + 32);
    body(bufB, bufA, kc + 32, kcn2);
  }

  // --- merge the two kv halves ---
  if (zz == 1) {
#pragma unroll
    for (int nt = 0; nt < 4; nt++)
#pragma unroll
      for (int rp = 0; rp < 2; rp++) {
        int d = nt * 16 + quad * 4 + rp * 2;
        f32x2 v2 = {acc[nt][rp * 2], acc[nt][rp * 2 + 1]};
        *(f32x2*)&CACC[qw][col][d] = v2;
      }
    if (quad == 0) {
      CML[qw][col][0] = m_r;
      CML[qw][col][1] = l_r;
    }
  }
  __syncthreads();
  if (zz == 0) {
    float m1 = CML[qw][col][0], l1 = CML[qw][col][1];
    float mm = fmaxf(m_r, m1);
    float e0 = __expf(m_r - mm), e1 = __expf(m1 - mm);
    float linv = 1.0f / (l_r * e0 + l1 * e1);
    _Float16* aop = ao + (size_t)(b * S_ + q) * HIDDEN + h * DK;
#pragma unroll
    for (int nt = 0; nt < 4; nt++)
#pragma unroll
      for (int rp = 0; rp < 2; rp++) {
        int d = nt * 16 + quad * 4 + rp * 2;
        f32x2 a1 = *(const f32x2*)&CACC[qw][col][d];
        float o0 = (acc[nt][rp * 2] * e0 + a1[0] * e1) * linv;
        float o1 = (acc[nt][rp * 2 + 1] * e0 + a1[1] * e1) * linv;
        half2_t o = {(_Float16)o0, (_Float16)o1};
        *(half2_t*)(aop + d) = o;
      }
  }
}

// ---------------- output projection ----------------
__global__ __launch_bounds__(256) void out_proj(
    const _Float16* __restrict__ ao, const _Float16* __restrict__ wo,
    const float* __restrict__ bo, float* __restrict__ out) {
  int m0 = blockIdx.x * 64;
  int n0 = blockIdx.y * 64;
  int tid = threadIdx.x, wave = tid >> 6, lane = tid & 63;
  int r16 = lane & 15, quad = lane >> 4;
  const _Float16* Ap = ao + (m0 + wave * 16 + r16) * HIDDEN + quad * 8;
  const _Float16* Wp = wo + (n0 + r16) * HIDDEN + quad * 8;
  f32x4 acc[4] = {};
  for (int k0 = 0; k0 < HIDDEN; k0 += 32) {
    half8 a = *(const half8*)(Ap + k0);
#pragma unroll
    for (int nt = 0; nt < 4; nt++) {
      half8 bfr = *(const half8*)(Wp + nt * 16 * HIDDEN + k0);
      acc[nt] = __builtin_amdgcn_mfma_f32_16x16x32_f16(a, bfr, acc[nt], 0, 0, 0);
    }
  }
#pragma unroll
  for (int nt = 0; nt < 4; nt++) {
    int gcol = n0 + nt * 16 + r16;
    float bv_ = bo[gcol];
#pragma unroll
    for (int r = 0; r < 4; r++) {
      int grow = m0 + wave * 16 + quad * 4 + r;
      out[grow * HIDDEN + gcol] = acc[nt][r] + bv_;
    }
  }
}

// ---------------- launch ----------------
extern "C" void kernel_launch(void* const* d_in, const int* in_sizes, int n_in,
                              void* d_out, int out_size, void* d_ws, size_t ws_size,
                              hipStream_t stream) {
  const float* q = (const float*)d_in[0];
  const float* k = (const float*)d_in[1];
  const float* v = (const float*)d_in[2];
  const float* attn_bias = (const float*)d_in[3];
  const int* gmask = (const int*)d_in[4];
  const float* subsq = (const float*)d_in[5];
  const float* Wq = (const float*)d_in[6];
  const float* bq = (const float*)d_in[7];
  const float* Wk = (const float*)d_in[8];
  const float* bk = (const float*)d_in[9];
  const float* Wv = (const float*)d_in[10];
  const float* bv = (const float*)d_in[11];
  const float* Wo = (const float*)d_in[12];
  const float* bo = (const float*)d_in[13];

  char* ws = (char*)d_ws;
  _Float16* q16 = (_Float16*)(ws + 0);
  _Float16* k16 = (_Float16*)(ws + 4194304);
  _Float16* v16 = (_Float16*)(ws + 8388608);
  _Float16* wq16 = (_Float16*)(ws + 12582912);
  _Float16* wk16 = (_Float16*)(ws + 13107200);
  _Float16* wv16 = (_Float16*)(ws + 13631488);
  _Float16* wo16 = (_Float16*)(ws + 14155776);
  _Float16* qhb = (_Float16*)(ws + 14680064);
  _Float16* khb = (_Float16*)(ws + 18874368);
  _Float16* vtb = (_Float16*)(ws + 23068672);
  _Float16* aob = (_Float16*)(ws + 27262976);

  cvt3<<<dim3(2048, 3), 256, 0, stream>>>(q, k, v, q16, k16, v16);
  cvt4<<<dim3(256, 4), 256, 0, stream>>>(Wq, Wk, Wv, Wo, wq16, wk16, wv16, wo16);
  proj_qkv<<<dim3(64, 24), 256, 0, stream>>>(q16, k16, v16, wq16, wk16, wv16,
                                             bq, bk, bv, qhb, khb, vtb);
  attn4<<<dim3(16, 32), 512, 0, stream>>>(qhb, khb, vtb, attn_bias, gmask,
                                          subsq, aob);
  out_proj<<<dim3(64, 8), 256, 0, stream>>>(aob, wo16, bo, (float*)d_out);
}

// Round 5
// 187.602 us; speedup vs baseline: 1.0697x; 1.0697x over previous
//
#include <hip/hip_runtime.h>

#define HIDDEN 512
#define HEADS 8
#define DK 64
#define S_ 1024
#define NEGV -1000000000.0f

typedef _Float16 half8 __attribute__((ext_vector_type(8)));
typedef _Float16 half4 __attribute__((ext_vector_type(4)));
typedef _Float16 half2_t __attribute__((ext_vector_type(2)));
typedef float f32x4 __attribute__((ext_vector_type(4)));
typedef float f32x2 __attribute__((ext_vector_type(2)));
typedef int i32x4 __attribute__((ext_vector_type(4)));

// ---------------- fp32 -> fp16 converters ----------------
__global__ __launch_bounds__(256) void cvt3(const float* __restrict__ a0,
                                            const float* __restrict__ a1,
                                            const float* __restrict__ a2,
                                            _Float16* o0, _Float16* o1, _Float16* o2) {
  const float* src = blockIdx.y == 0 ? a0 : (blockIdx.y == 1 ? a1 : a2);
  _Float16* dst = blockIdx.y == 0 ? o0 : (blockIdx.y == 1 ? o1 : o2);
  int i = (blockIdx.x * 256 + threadIdx.x) * 4;
  float4 v = *(const float4*)(src + i);
  half4 h = {(_Float16)v.x, (_Float16)v.y, (_Float16)v.z, (_Float16)v.w};
  *(half4*)(dst + i) = h;
}

__global__ __launch_bounds__(256) void cvt4(const float* __restrict__ a0,
                                            const float* __restrict__ a1,
                                            const float* __restrict__ a2,
                                            const float* __restrict__ a3,
                                            _Float16* o0, _Float16* o1, _Float16* o2, _Float16* o3) {
  const float* src = blockIdx.y == 0 ? a0 : (blockIdx.y == 1 ? a1 : (blockIdx.y == 2 ? a2 : a3));
  _Float16* dst = blockIdx.y == 0 ? o0 : (blockIdx.y == 1 ? o1 : (blockIdx.y == 2 ? o2 : o3));
  int i = (blockIdx.x * 256 + threadIdx.x) * 4;
  float4 v = *(const float4*)(src + i);
  half4 h = {(_Float16)v.x, (_Float16)v.y, (_Float16)v.z, (_Float16)v.w};
  *(half4*)(dst + i) = h;
}

// ---------------- fuse gmask+subsq -> fp16 (per b, shared across heads) ----------------
__global__ __launch_bounds__(256) void fusemask(const int* __restrict__ gm,
                                                const float* __restrict__ sq,
                                                _Float16* __restrict__ msk) {
  int i = (blockIdx.x * 256 + threadIdx.x) * 4;
  i32x4 g = *(const i32x4*)(gm + i);
  f32x4 s = *(const f32x4*)(sq + i);
  half4 o;
#pragma unroll
  for (int j = 0; j < 4; j++)
    o[j] = (_Float16)(g[j] == 0 ? -30000.0f : s[j]);
  *(half4*)(msk + i) = o;
}

// ---------------- fused QKV projection ----------------
__global__ __launch_bounds__(256) void proj_qkv(
    const _Float16* __restrict__ q16, const _Float16* __restrict__ k16,
    const _Float16* __restrict__ v16,
    const _Float16* __restrict__ wq, const _Float16* __restrict__ wk,
    const _Float16* __restrict__ wv,
    const float* __restrict__ bq, const float* __restrict__ bk,
    const float* __restrict__ bv,
    _Float16* __restrict__ qh, _Float16* __restrict__ kh, _Float16* __restrict__ vt) {
  int m0 = blockIdx.x * 64;
  int nb = blockIdx.y;
  int which = nb >> 3;
  int n0 = (nb & 7) * 64;
  const _Float16* X = which == 0 ? q16 : (which == 1 ? k16 : v16);
  const _Float16* W = which == 0 ? wq : (which == 1 ? wk : wv);
  const float* bias = which == 0 ? bq : (which == 1 ? bk : bv);

  int tid = threadIdx.x;
  int wave = tid >> 6, lane = tid & 63;
  int r16 = lane & 15, quad = lane >> 4;

  const _Float16* Xp = X + (m0 + wave * 16 + r16) * HIDDEN + quad * 8;
  const _Float16* Wp = W + (n0 + r16) * HIDDEN + quad * 8;

  f32x4 acc[4] = {};
  for (int k0 = 0; k0 < HIDDEN; k0 += 32) {
    half8 a = *(const half8*)(Xp + k0);
#pragma unroll
    for (int nt = 0; nt < 4; nt++) {
      half8 bfr = *(const half8*)(Wp + nt * 16 * HIDDEN + k0);
      acc[nt] = __builtin_amdgcn_mfma_f32_16x16x32_f16(a, bfr, acc[nt], 0, 0, 0);
    }
  }

  __shared__ _Float16 T[64][72];

  if (which < 2) {
    _Float16* OUT = which == 0 ? qh : kh;
    float scale = which == 0 ? 0.125f : 1.0f;  // DK^-0.5 = 1/8
#pragma unroll
    for (int nt = 0; nt < 4; nt++) {
      int gcol = n0 + nt * 16 + r16;
      float bv_ = bias[gcol];
      int h = gcol >> 6, d = gcol & 63;
#pragma unroll
      for (int r = 0; r < 4; r++) {
        int grow = m0 + wave * 16 + quad * 4 + r;
        int bb = grow >> 10, s = grow & 1023;
        float val = (acc[nt][r] + bv_) * scale;
        OUT[((bb * HEADS + h) * S_ + s) * DK + d] = (_Float16)val;
      }
    }
  } else {
    // V: transpose 64x64 tile via LDS, write vt[b][h][d][s]
#pragma unroll
    for (int nt = 0; nt < 4; nt++) {
      int lc = nt * 16 + r16;
      float bv_ = bias[n0 + lc];
#pragma unroll
      for (int r = 0; r < 4; r++) {
        int lr = wave * 16 + quad * 4 + r;
        T[lr][lc] = (_Float16)(acc[nt][r] + bv_);
      }
    }
    __syncthreads();
    int dl = tid >> 2;
    int s4 = (tid & 3) * 16;
    _Float16 tmp[16];
#pragma unroll
    for (int i = 0; i < 16; i++) tmp[i] = T[s4 + i][dl];
    int h = n0 >> 6;
    int bb = m0 >> 10;
    int s0 = m0 & 1023;
    _Float16* p = vt + ((bb * HEADS + h) * DK + dl) * S_ + s0 + s4;
    *(half8*)(p) = *(half8*)(tmp);
    *(half8*)(p + 8) = *(half8*)(tmp + 8);
  }
}

// ---------------- attention v5: K/V-first load order + light HBM prefetch ----------------
// grid (S/64, B*H); 8 waves. Waves 0-3: kv [0,512), 4-7: [512,1024).
// Per step: issue K/V (L2) loads, then next step's bias/msk (HBM) loads, then
// compute using the PREVIOUS prefetch. In-order vmcnt retirement means the
// K-wait only covers the 6 outstanding prefetch loads (which had a full step
// to land), never the current compute's operands.
struct PBuf {
  f32x4 bi0, bi1;
  half4 mk0, mk1;
};

__global__ __launch_bounds__(512) void attn5(
    const _Float16* __restrict__ qh, const _Float16* __restrict__ kh,
    const _Float16* __restrict__ vt,
    const float* __restrict__ attn_bias, const _Float16* __restrict__ msk,
    _Float16* __restrict__ ao) {
  int bh = blockIdx.y;
  int b = bh >> 3, h = bh & 7;
  int tid = threadIdx.x;
  int wave = tid >> 6, lane = tid & 63;
  int col = lane & 15, quad = lane >> 4;
  int qw = wave & 3, zz = wave >> 2;
  int q = blockIdx.x * 64 + qw * 16 + col;

  __shared__ unsigned P2[8][16][20];
  __shared__ float CACC[4][16][66];
  __shared__ float CML[4][16][2];

  const _Float16* Q = qh + ((size_t)bh * S_ + q) * DK;
  const _Float16* K = kh + (size_t)bh * S_ * DK;
  const _Float16* V = vt + (size_t)bh * DK * S_;
  const float* BI = attn_bias + ((size_t)bh * S_ + q) * S_;
  const _Float16* MS = msk + ((size_t)b * S_ + q) * S_;

  half8 qf0 = *(const half8*)(Q + quad * 8);
  half8 qf1 = *(const half8*)(Q + 32 + quad * 8);

  f32x4 acc[4] = {};  // out^T: acc[nt][r] = out[d = nt*16+quad*4+r][q]
  float m_r = -1e38f, l_r = 0.0f;

  int kv0 = zz * 512;

  PBuf bufA, bufB;
  {
    int kc = kv0;
    bufA.bi0 = *(const f32x4*)(BI + kc + quad * 4);
    bufA.bi1 = *(const f32x4*)(BI + kc + 16 + quad * 4);
    bufA.mk0 = *(const half4*)(MS + kc + quad * 4);
    bufA.mk1 = *(const half4*)(MS + kc + 16 + quad * 4);
  }

  auto body = [&](PBuf& R, PBuf& W, int kc, int kcn) __attribute__((always_inline)) {
    // --- current step K/V loads FIRST (L2-resident) ---
    const _Float16* Kp0 = K + (size_t)(kc + col) * DK + quad * 8;
    const _Float16* Kp1 = K + (size_t)(kc + 16 + col) * DK + quad * 8;
    half8 kf00 = *(const half8*)(Kp0);
    half8 kf01 = *(const half8*)(Kp0 + 32);
    half8 kf10 = *(const half8*)(Kp1);
    half8 kf11 = *(const half8*)(Kp1 + 32);

    const _Float16* Vb = V + kc + quad * 8;
    half8 vf0 = *(const half8*)(Vb + (0 * 16 + col) * S_);
    half8 vf1 = *(const half8*)(Vb + (1 * 16 + col) * S_);
    half8 vf2 = *(const half8*)(Vb + (2 * 16 + col) * S_);
    half8 vf3 = *(const half8*)(Vb + (3 * 16 + col) * S_);

    // --- THEN issue next step's HBM loads (not consumed this body) ---
    W.bi0 = *(const f32x4*)(BI + kcn + quad * 4);
    W.bi1 = *(const f32x4*)(BI + kcn + 16 + quad * 4);
    W.mk0 = *(const half4*)(MS + kcn + quad * 4);
    W.mk1 = *(const half4*)(MS + kcn + 16 + quad * 4);

    // --- QK^T swapped: S^T[k][q] (waits only K + outstanding prefetch) ---
    f32x4 s0 = {}, s1 = {};
    s0 = __builtin_amdgcn_mfma_f32_16x16x32_f16(kf00, qf0, s0, 0, 0, 0);
    s0 = __builtin_amdgcn_mfma_f32_16x16x32_f16(kf01, qf1, s0, 0, 0, 0);
    s1 = __builtin_amdgcn_mfma_f32_16x16x32_f16(kf10, qf0, s1, 0, 0, 0);
    s1 = __builtin_amdgcn_mfma_f32_16x16x32_f16(kf11, qf1, s1, 0, 0, 0);

    float x0[4], x1[4];
#pragma unroll
    for (int r = 0; r < 4; r++) {
      x0[r] = s0[r] + R.bi0[r] + (float)R.mk0[r];
      x1[r] = s1[r] + R.bi1[r] + (float)R.mk1[r];
    }

    float mx = fmaxf(fmaxf(fmaxf(x0[0], x0[1]), fmaxf(x0[2], x0[3])),
                     fmaxf(fmaxf(x1[0], x1[1]), fmaxf(x1[2], x1[3])));
    mx = fmaxf(mx, __shfl_xor(mx, 16));
    mx = fmaxf(mx, __shfl_xor(mx, 32));
    float mnew = fmaxf(m_r, mx);
    float f = __expf(m_r - mnew);
    float p0[4], p1[4];
    float ps = 0.0f;
#pragma unroll
    for (int r = 0; r < 4; r++) {
      p0[r] = __expf(x0[r] - mnew);
      p1[r] = __expf(x1[r] - mnew);
      ps += p0[r] + p1[r];
    }
    ps += __shfl_xor(ps, 16);
    ps += __shfl_xor(ps, 32);
    l_r = l_r * f + ps;
    m_r = mnew;
#pragma unroll
    for (int nt = 0; nt < 4; nt++) acc[nt] *= f;

    half2_t c0 = {(_Float16)p0[0], (_Float16)p0[1]};
    half2_t c1 = {(_Float16)p0[2], (_Float16)p0[3]};
    half2_t c2 = {(_Float16)p1[0], (_Float16)p1[1]};
    half2_t c3 = {(_Float16)p1[2], (_Float16)p1[3]};
    P2[wave][col][quad * 2 + 0] = __builtin_bit_cast(unsigned, c0);
    P2[wave][col][quad * 2 + 1] = __builtin_bit_cast(unsigned, c1);
    P2[wave][col][8 + quad * 2 + 0] = __builtin_bit_cast(unsigned, c2);
    P2[wave][col][8 + quad * 2 + 1] = __builtin_bit_cast(unsigned, c3);

    half8 pf = *(const half8*)&P2[wave][col][quad * 4];

    acc[0] = __builtin_amdgcn_mfma_f32_16x16x32_f16(vf0, pf, acc[0], 0, 0, 0);
    acc[1] = __builtin_amdgcn_mfma_f32_16x16x32_f16(vf1, pf, acc[1], 0, 0, 0);
    acc[2] = __builtin_amdgcn_mfma_f32_16x16x32_f16(vf2, pf, acc[2], 0, 0, 0);
    acc[3] = __builtin_amdgcn_mfma_f32_16x16x32_f16(vf3, pf, acc[3], 0, 0, 0);
  };

  for (int ii = 0; ii < 8; ii++) {
    int kc = kv0 + ii * 64;
    int kcn2 = (ii == 7) ? kv0 : kc + 64;  // wrap: last prefetch unused
    body(bufA, bufB, kc, kc + 32);
    body(bufB, bufA, kc + 32, kcn2);
  }

  // --- merge the two kv halves ---
  if (zz == 1) {
#pragma unroll
    for (int nt = 0; nt < 4; nt++)
#pragma unroll
      for (int rp = 0; rp < 2; rp++) {
        int d = nt * 16 + quad * 4 + rp * 2;
        f32x2 v2 = {acc[nt][rp * 2], acc[nt][rp * 2 + 1]};
        *(f32x2*)&CACC[qw][col][d] = v2;
      }
    if (quad == 0) {
      CML[qw][col][0] = m_r;
      CML[qw][col][1] = l_r;
    }
  }
  __syncthreads();
  if (zz == 0) {
    float m1 = CML[qw][col][0], l1 = CML[qw][col][1];
    float mm = fmaxf(m_r, m1);
    float e0 = __expf(m_r - mm), e1 = __expf(m1 - mm);
    float linv = 1.0f / (l_r * e0 + l1 * e1);
    _Float16* aop = ao + (size_t)(b * S_ + q) * HIDDEN + h * DK;
#pragma unroll
    for (int nt = 0; nt < 4; nt++)
#pragma unroll
      for (int rp = 0; rp < 2; rp++) {
        int d = nt * 16 + quad * 4 + rp * 2;
        f32x2 a1 = *(const f32x2*)&CACC[qw][col][d];
        float o0 = (acc[nt][rp * 2] * e0 + a1[0] * e1) * linv;
        float o1 = (acc[nt][rp * 2 + 1] * e0 + a1[1] * e1) * linv;
        half2_t o = {(_Float16)o0, (_Float16)o1};
        *(half2_t*)(aop + d) = o;
      }
  }
}

// ---------------- output projection ----------------
__global__ __launch_bounds__(256) void out_proj(
    const _Float16* __restrict__ ao, const _Float16* __restrict__ wo,
    const float* __restrict__ bo, float* __restrict__ out) {
  int m0 = blockIdx.x * 64;
  int n0 = blockIdx.y * 64;
  int tid = threadIdx.x, wave = tid >> 6, lane = tid & 63;
  int r16 = lane & 15, quad = lane >> 4;
  const _Float16* Ap = ao + (m0 + wave * 16 + r16) * HIDDEN + quad * 8;
  const _Float16* Wp = wo + (n0 + r16) * HIDDEN + quad * 8;
  f32x4 acc[4] = {};
  for (int k0 = 0; k0 < HIDDEN; k0 += 32) {
    half8 a = *(const half8*)(Ap + k0);
#pragma unroll
    for (int nt = 0; nt < 4; nt++) {
      half8 bfr = *(const half8*)(Wp + nt * 16 * HIDDEN + k0);
      acc[nt] = __builtin_amdgcn_mfma_f32_16x16x32_f16(a, bfr, acc[nt], 0, 0, 0);
    }
  }
#pragma unroll
  for (int nt = 0; nt < 4; nt++) {
    int gcol = n0 + nt * 16 + r16;
    float bv_ = bo[gcol];
#pragma unroll
    for (int r = 0; r < 4; r++) {
      int grow = m0 + wave * 16 + quad * 4 + r;
      out[grow * HIDDEN + gcol] = acc[nt][r] + bv_;
    }
  }
}

// ---------------- launch ----------------
extern "C" void kernel_launch(void* const* d_in, const int* in_sizes, int n_in,
                              void* d_out, int out_size, void* d_ws, size_t ws_size,
                              hipStream_t stream) {
  const float* q = (const float*)d_in[0];
  const float* k = (const float*)d_in[1];
  const float* v = (const float*)d_in[2];
  const float* attn_bias = (const float*)d_in[3];
  const int* gmask = (const int*)d_in[4];
  const float* subsq = (const float*)d_in[5];
  const float* Wq = (const float*)d_in[6];
  const float* bq = (const float*)d_in[7];
  const float* Wk = (const float*)d_in[8];
  const float* bk = (const float*)d_in[9];
  const float* Wv = (const float*)d_in[10];
  const float* bv = (const float*)d_in[11];
  const float* Wo = (const float*)d_in[12];
  const float* bo = (const float*)d_in[13];

  char* ws = (char*)d_ws;
  _Float16* q16 = (_Float16*)(ws + 0);
  _Float16* k16 = (_Float16*)(ws + 4194304);
  _Float16* v16 = (_Float16*)(ws + 8388608);
  _Float16* wq16 = (_Float16*)(ws + 12582912);
  _Float16* wk16 = (_Float16*)(ws + 13107200);
  _Float16* wv16 = (_Float16*)(ws + 13631488);
  _Float16* wo16 = (_Float16*)(ws + 14155776);
  _Float16* qhb = (_Float16*)(ws + 14680064);
  _Float16* khb = (_Float16*)(ws + 18874368);
  _Float16* vtb = (_Float16*)(ws + 23068672);
  _Float16* aob = (_Float16*)(ws + 27262976);
  // msk16 overlays q16/k16 region (8 MB, dead after proj_qkv)
  _Float16* msk16 = (_Float16*)(ws + 0);

  cvt3<<<dim3(2048, 3), 256, 0, stream>>>(q, k, v, q16, k16, v16);
  cvt4<<<dim3(256, 4), 256, 0, stream>>>(Wq, Wk, Wv, Wo, wq16, wk16, wv16, wo16);
  proj_qkv<<<dim3(64, 24), 256, 0, stream>>>(q16, k16, v16, wq16, wk16, wv16,
                                             bq, bk, bv, qhb, khb, vtb);
  fusemask<<<dim3(4096), 256, 0, stream>>>(gmask, subsq, msk16);
  attn5<<<dim3(16, 32), 512, 0, stream>>>(qhb, khb, vtb, attn_bias, msk16, aob);
  out_proj<<<dim3(64, 8), 256, 0, stream>>>(aob, wo16, bo, (float*)d_out);
}

// Round 6
// 187.075 us; speedup vs baseline: 1.0727x; 1.0028x over previous
//
#include <hip/hip_runtime.h>

#define HIDDEN 512
#define HEADS 8
#define DK 64
#define S_ 1024
#define NEGV -1000000000.0f

typedef _Float16 half8 __attribute__((ext_vector_type(8)));
typedef _Float16 half4 __attribute__((ext_vector_type(4)));
typedef _Float16 half2_t __attribute__((ext_vector_type(2)));
typedef float f32x4 __attribute__((ext_vector_type(4)));
typedef float f32x2 __attribute__((ext_vector_type(2)));
typedef int i32x4 __attribute__((ext_vector_type(4)));

// ---------------- fp32 -> fp16 converters ----------------
__global__ __launch_bounds__(256) void cvt3(const float* __restrict__ a0,
                                            const float* __restrict__ a1,
                                            const float* __restrict__ a2,
                                            _Float16* o0, _Float16* o1, _Float16* o2) {
  const float* src = blockIdx.y == 0 ? a0 : (blockIdx.y == 1 ? a1 : a2);
  _Float16* dst = blockIdx.y == 0 ? o0 : (blockIdx.y == 1 ? o1 : o2);
  int i = (blockIdx.x * 256 + threadIdx.x) * 4;
  float4 v = *(const float4*)(src + i);
  half4 h = {(_Float16)v.x, (_Float16)v.y, (_Float16)v.z, (_Float16)v.w};
  *(half4*)(dst + i) = h;
}

__global__ __launch_bounds__(256) void cvt4(const float* __restrict__ a0,
                                            const float* __restrict__ a1,
                                            const float* __restrict__ a2,
                                            const float* __restrict__ a3,
                                            _Float16* o0, _Float16* o1, _Float16* o2, _Float16* o3) {
  const float* src = blockIdx.y == 0 ? a0 : (blockIdx.y == 1 ? a1 : (blockIdx.y == 2 ? a2 : a3));
  _Float16* dst = blockIdx.y == 0 ? o0 : (blockIdx.y == 1 ? o1 : (blockIdx.y == 2 ? o2 : o3));
  int i = (blockIdx.x * 256 + threadIdx.x) * 4;
  float4 v = *(const float4*)(src + i);
  half4 h = {(_Float16)v.x, (_Float16)v.y, (_Float16)v.z, (_Float16)v.w};
  *(half4*)(dst + i) = h;
}

// ---------------- fuse gmask+subsq -> fp16 (per b, shared across heads) ----------------
__global__ __launch_bounds__(256) void fusemask(const int* __restrict__ gm,
                                                const float* __restrict__ sq,
                                                _Float16* __restrict__ msk) {
  int i = (blockIdx.x * 256 + threadIdx.x) * 4;
  i32x4 g = *(const i32x4*)(gm + i);
  f32x4 s = *(const f32x4*)(sq + i);
  half4 o;
#pragma unroll
  for (int j = 0; j < 4; j++)
    o[j] = (_Float16)(g[j] == 0 ? -30000.0f : s[j]);
  *(half4*)(msk + i) = o;
}

// ---------------- fused QKV projection ----------------
__global__ __launch_bounds__(256) void proj_qkv(
    const _Float16* __restrict__ q16, const _Float16* __restrict__ k16,
    const _Float16* __restrict__ v16,
    const _Float16* __restrict__ wq, const _Float16* __restrict__ wk,
    const _Float16* __restrict__ wv,
    const float* __restrict__ bq, const float* __restrict__ bk,
    const float* __restrict__ bv,
    _Float16* __restrict__ qh, _Float16* __restrict__ kh, _Float16* __restrict__ vt) {
  int m0 = blockIdx.x * 64;
  int nb = blockIdx.y;
  int which = nb >> 3;
  int n0 = (nb & 7) * 64;
  const _Float16* X = which == 0 ? q16 : (which == 1 ? k16 : v16);
  const _Float16* W = which == 0 ? wq : (which == 1 ? wk : wv);
  const float* bias = which == 0 ? bq : (which == 1 ? bk : bv);

  int tid = threadIdx.x;
  int wave = tid >> 6, lane = tid & 63;
  int r16 = lane & 15, quad = lane >> 4;

  const _Float16* Xp = X + (m0 + wave * 16 + r16) * HIDDEN + quad * 8;
  const _Float16* Wp = W + (n0 + r16) * HIDDEN + quad * 8;

  f32x4 acc[4] = {};
  for (int k0 = 0; k0 < HIDDEN; k0 += 32) {
    half8 a = *(const half8*)(Xp + k0);
#pragma unroll
    for (int nt = 0; nt < 4; nt++) {
      half8 bfr = *(const half8*)(Wp + nt * 16 * HIDDEN + k0);
      acc[nt] = __builtin_amdgcn_mfma_f32_16x16x32_f16(a, bfr, acc[nt], 0, 0, 0);
    }
  }

  __shared__ _Float16 T[64][72];

  if (which < 2) {
    _Float16* OUT = which == 0 ? qh : kh;
    float scale = which == 0 ? 0.125f : 1.0f;  // DK^-0.5 = 1/8
#pragma unroll
    for (int nt = 0; nt < 4; nt++) {
      int gcol = n0 + nt * 16 + r16;
      float bv_ = bias[gcol];
      int h = gcol >> 6, d = gcol & 63;
#pragma unroll
      for (int r = 0; r < 4; r++) {
        int grow = m0 + wave * 16 + quad * 4 + r;
        int bb = grow >> 10, s = grow & 1023;
        float val = (acc[nt][r] + bv_) * scale;
        OUT[((bb * HEADS + h) * S_ + s) * DK + d] = (_Float16)val;
      }
    }
  } else {
    // V: transpose 64x64 tile via LDS, write vt[b][h][d][s]
#pragma unroll
    for (int nt = 0; nt < 4; nt++) {
      int lc = nt * 16 + r16;
      float bv_ = bias[n0 + lc];
#pragma unroll
      for (int r = 0; r < 4; r++) {
        int lr = wave * 16 + quad * 4 + r;
        T[lr][lc] = (_Float16)(acc[nt][r] + bv_);
      }
    }
    __syncthreads();
    int dl = tid >> 2;
    int s4 = (tid & 3) * 16;
    _Float16 tmp[16];
#pragma unroll
    for (int i = 0; i < 16; i++) tmp[i] = T[s4 + i][dl];
    int h = n0 >> 6;
    int bb = m0 >> 10;
    int s0 = m0 & 1023;
    _Float16* p = vt + ((bb * HEADS + h) * DK + dl) * S_ + s0 + s4;
    *(half8*)(p) = *(half8*)(tmp);
    *(half8*)(p + 8) = *(half8*)(tmp + 8);
  }
}

// ---------------- attention v6: v5 + register headroom (launch_bounds 512,2) ----------------
// The ONLY change vs v5: allow up to 256 VGPRs so one full body's 12 loads can
// be in flight concurrently instead of being serialized at VGPR=56.
struct PBuf {
  f32x4 bi0, bi1;
  half4 mk0, mk1;
};

__global__ __launch_bounds__(512, 2) void attn6(
    const _Float16* __restrict__ qh, const _Float16* __restrict__ kh,
    const _Float16* __restrict__ vt,
    const float* __restrict__ attn_bias, const _Float16* __restrict__ msk,
    _Float16* __restrict__ ao) {
  int bh = blockIdx.y;
  int b = bh >> 3, h = bh & 7;
  int tid = threadIdx.x;
  int wave = tid >> 6, lane = tid & 63;
  int col = lane & 15, quad = lane >> 4;
  int qw = wave & 3, zz = wave >> 2;
  int q = blockIdx.x * 64 + qw * 16 + col;

  __shared__ unsigned P2[8][16][20];
  __shared__ float CACC[4][16][66];
  __shared__ float CML[4][16][2];

  const _Float16* Q = qh + ((size_t)bh * S_ + q) * DK;
  const _Float16* K = kh + (size_t)bh * S_ * DK;
  const _Float16* V = vt + (size_t)bh * DK * S_;
  const float* BI = attn_bias + ((size_t)bh * S_ + q) * S_;
  const _Float16* MS = msk + ((size_t)b * S_ + q) * S_;

  half8 qf0 = *(const half8*)(Q + quad * 8);
  half8 qf1 = *(const half8*)(Q + 32 + quad * 8);

  f32x4 acc[4] = {};  // out^T: acc[nt][r] = out[d = nt*16+quad*4+r][q]
  float m_r = -1e38f, l_r = 0.0f;

  int kv0 = zz * 512;

  PBuf bufA, bufB;
  {
    int kc = kv0;
    bufA.bi0 = *(const f32x4*)(BI + kc + quad * 4);
    bufA.bi1 = *(const f32x4*)(BI + kc + 16 + quad * 4);
    bufA.mk0 = *(const half4*)(MS + kc + quad * 4);
    bufA.mk1 = *(const half4*)(MS + kc + 16 + quad * 4);
  }

  auto body = [&](PBuf& R, PBuf& W, int kc, int kcn) __attribute__((always_inline)) {
    // --- current step K/V loads FIRST (L2-resident) ---
    const _Float16* Kp0 = K + (size_t)(kc + col) * DK + quad * 8;
    const _Float16* Kp1 = K + (size_t)(kc + 16 + col) * DK + quad * 8;
    half8 kf00 = *(const half8*)(Kp0);
    half8 kf01 = *(const half8*)(Kp0 + 32);
    half8 kf10 = *(const half8*)(Kp1);
    half8 kf11 = *(const half8*)(Kp1 + 32);

    const _Float16* Vb = V + kc + quad * 8;
    half8 vf0 = *(const half8*)(Vb + (0 * 16 + col) * S_);
    half8 vf1 = *(const half8*)(Vb + (1 * 16 + col) * S_);
    half8 vf2 = *(const half8*)(Vb + (2 * 16 + col) * S_);
    half8 vf3 = *(const half8*)(Vb + (3 * 16 + col) * S_);

    // --- THEN issue next step's HBM loads (not consumed this body) ---
    W.bi0 = *(const f32x4*)(BI + kcn + quad * 4);
    W.bi1 = *(const f32x4*)(BI + kcn + 16 + quad * 4);
    W.mk0 = *(const half4*)(MS + kcn + quad * 4);
    W.mk1 = *(const half4*)(MS + kcn + 16 + quad * 4);

    // --- QK^T swapped: S^T[k][q] ---
    f32x4 s0 = {}, s1 = {};
    s0 = __builtin_amdgcn_mfma_f32_16x16x32_f16(kf00, qf0, s0, 0, 0, 0);
    s0 = __builtin_amdgcn_mfma_f32_16x16x32_f16(kf01, qf1, s0, 0, 0, 0);
    s1 = __builtin_amdgcn_mfma_f32_16x16x32_f16(kf10, qf0, s1, 0, 0, 0);
    s1 = __builtin_amdgcn_mfma_f32_16x16x32_f16(kf11, qf1, s1, 0, 0, 0);

    float x0[4], x1[4];
#pragma unroll
    for (int r = 0; r < 4; r++) {
      x0[r] = s0[r] + R.bi0[r] + (float)R.mk0[r];
      x1[r] = s1[r] + R.bi1[r] + (float)R.mk1[r];
    }

    float mx = fmaxf(fmaxf(fmaxf(x0[0], x0[1]), fmaxf(x0[2], x0[3])),
                     fmaxf(fmaxf(x1[0], x1[1]), fmaxf(x1[2], x1[3])));
    mx = fmaxf(mx, __shfl_xor(mx, 16));
    mx = fmaxf(mx, __shfl_xor(mx, 32));
    float mnew = fmaxf(m_r, mx);
    float f = __expf(m_r - mnew);
    float p0[4], p1[4];
    float ps = 0.0f;
#pragma unroll
    for (int r = 0; r < 4; r++) {
      p0[r] = __expf(x0[r] - mnew);
      p1[r] = __expf(x1[r] - mnew);
      ps += p0[r] + p1[r];
    }
    ps += __shfl_xor(ps, 16);
    ps += __shfl_xor(ps, 32);
    l_r = l_r * f + ps;
    m_r = mnew;
#pragma unroll
    for (int nt = 0; nt < 4; nt++) acc[nt] *= f;

    half2_t c0 = {(_Float16)p0[0], (_Float16)p0[1]};
    half2_t c1 = {(_Float16)p0[2], (_Float16)p0[3]};
    half2_t c2 = {(_Float16)p1[0], (_Float16)p1[1]};
    half2_t c3 = {(_Float16)p1[2], (_Float16)p1[3]};
    P2[wave][col][quad * 2 + 0] = __builtin_bit_cast(unsigned, c0);
    P2[wave][col][quad * 2 + 1] = __builtin_bit_cast(unsigned, c1);
    P2[wave][col][8 + quad * 2 + 0] = __builtin_bit_cast(unsigned, c2);
    P2[wave][col][8 + quad * 2 + 1] = __builtin_bit_cast(unsigned, c3);

    half8 pf = *(const half8*)&P2[wave][col][quad * 4];

    acc[0] = __builtin_amdgcn_mfma_f32_16x16x32_f16(vf0, pf, acc[0], 0, 0, 0);
    acc[1] = __builtin_amdgcn_mfma_f32_16x16x32_f16(vf1, pf, acc[1], 0, 0, 0);
    acc[2] = __builtin_amdgcn_mfma_f32_16x16x32_f16(vf2, pf, acc[2], 0, 0, 0);
    acc[3] = __builtin_amdgcn_mfma_f32_16x16x32_f16(vf3, pf, acc[3], 0, 0, 0);
  };

  for (int ii = 0; ii < 8; ii++) {
    int kc = kv0 + ii * 64;
    int kcn2 = (ii == 7) ? kv0 : kc + 64;  // wrap: last prefetch unused
    body(bufA, bufB, kc, kc + 32);
    body(bufB, bufA, kc + 32, kcn2);
  }

  // --- merge the two kv halves ---
  if (zz == 1) {
#pragma unroll
    for (int nt = 0; nt < 4; nt++)
#pragma unroll
      for (int rp = 0; rp < 2; rp++) {
        int d = nt * 16 + quad * 4 + rp * 2;
        f32x2 v2 = {acc[nt][rp * 2], acc[nt][rp * 2 + 1]};
        *(f32x2*)&CACC[qw][col][d] = v2;
      }
    if (quad == 0) {
      CML[qw][col][0] = m_r;
      CML[qw][col][1] = l_r;
    }
  }
  __syncthreads();
  if (zz == 0) {
    float m1 = CML[qw][col][0], l1 = CML[qw][col][1];
    float mm = fmaxf(m_r, m1);
    float e0 = __expf(m_r - mm), e1 = __expf(m1 - mm);
    float linv = 1.0f / (l_r * e0 + l1 * e1);
    _Float16* aop = ao + (size_t)(b * S_ + q) * HIDDEN + h * DK;
#pragma unroll
    for (int nt = 0; nt < 4; nt++)
#pragma unroll
      for (int rp = 0; rp < 2; rp++) {
        int d = nt * 16 + quad * 4 + rp * 2;
        f32x2 a1 = *(const f32x2*)&CACC[qw][col][d];
        float o0 = (acc[nt][rp * 2] * e0 + a1[0] * e1) * linv;
        float o1 = (acc[nt][rp * 2 + 1] * e0 + a1[1] * e1) * linv;
        half2_t o = {(_Float16)o0, (_Float16)o1};
        *(half2_t*)(aop + d) = o;
      }
  }
}

// ---------------- output projection ----------------
__global__ __launch_bounds__(256) void out_proj(
    const _Float16* __restrict__ ao, const _Float16* __restrict__ wo,
    const float* __restrict__ bo, float* __restrict__ out) {
  int m0 = blockIdx.x * 64;
  int n0 = blockIdx.y * 64;
  int tid = threadIdx.x, wave = tid >> 6, lane = tid & 63;
  int r16 = lane & 15, quad = lane >> 4;
  const _Float16* Ap = ao + (m0 + wave * 16 + r16) * HIDDEN + quad * 8;
  const _Float16* Wp = wo + (n0 + r16) * HIDDEN + quad * 8;
  f32x4 acc[4] = {};
  for (int k0 = 0; k0 < HIDDEN; k0 += 32) {
    half8 a = *(const half8*)(Ap + k0);
#pragma unroll
    for (int nt = 0; nt < 4; nt++) {
      half8 bfr = *(const half8*)(Wp + nt * 16 * HIDDEN + k0);
      acc[nt] = __builtin_amdgcn_mfma_f32_16x16x32_f16(a, bfr, acc[nt], 0, 0, 0);
    }
  }
#pragma unroll
  for (int nt = 0; nt < 4; nt++) {
    int gcol = n0 + nt * 16 + r16;
    float bv_ = bo[gcol];
#pragma unroll
    for (int r = 0; r < 4; r++) {
      int grow = m0 + wave * 16 + quad * 4 + r;
      out[grow * HIDDEN + gcol] = acc[nt][r] + bv_;
    }
  }
}

// ---------------- launch ----------------
extern "C" void kernel_launch(void* const* d_in, const int* in_sizes, int n_in,
                              void* d_out, int out_size, void* d_ws, size_t ws_size,
                              hipStream_t stream) {
  const float* q = (const float*)d_in[0];
  const float* k = (const float*)d_in[1];
  const float* v = (const float*)d_in[2];
  const float* attn_bias = (const float*)d_in[3];
  const int* gmask = (const int*)d_in[4];
  const float* subsq = (const float*)d_in[5];
  const float* Wq = (const float*)d_in[6];
  const float* bq = (const float*)d_in[7];
  const float* Wk = (const float*)d_in[8];
  const float* bk = (const float*)d_in[9];
  const float* Wv = (const float*)d_in[10];
  const float* bv = (const float*)d_in[11];
  const float* Wo = (const float*)d_in[12];
  const float* bo = (const float*)d_in[13];

  char* ws = (char*)d_ws;
  _Float16* q16 = (_Float16*)(ws + 0);
  _Float16* k16 = (_Float16*)(ws + 4194304);
  _Float16* v16 = (_Float16*)(ws + 8388608);
  _Float16* wq16 = (_Float16*)(ws + 12582912);
  _Float16* wk16 = (_Float16*)(ws + 13107200);
  _Float16* wv16 = (_Float16*)(ws + 13631488);
  _Float16* wo16 = (_Float16*)(ws + 14155776);
  _Float16* qhb = (_Float16*)(ws + 14680064);
  _Float16* khb = (_Float16*)(ws + 18874368);
  _Float16* vtb = (_Float16*)(ws + 23068672);
  _Float16* aob = (_Float16*)(ws + 27262976);
  // msk16 overlays q16/k16 region (8 MB, dead after proj_qkv)
  _Float16* msk16 = (_Float16*)(ws + 0);

  cvt3<<<dim3(2048, 3), 256, 0, stream>>>(q, k, v, q16, k16, v16);
  cvt4<<<dim3(256, 4), 256, 0, stream>>>(Wq, Wk, Wv, Wo, wq16, wk16, wv16, wo16);
  proj_qkv<<<dim3(64, 24), 256, 0, stream>>>(q16, k16, v16, wq16, wk16, wv16,
                                             bq, bk, bv, qhb, khb, vtb);
  fusemask<<<dim3(4096), 256, 0, stream>>>(gmask, subsq, msk16);
  attn6<<<dim3(16, 32), 512, 0, stream>>>(qhb, khb, vtb, attn_bias, msk16, aob);
  out_proj<<<dim3(64, 8), 256, 0, stream>>>(aob, wo16, bo, (float*)d_out);
}

// Round 7
// 166.069 us; speedup vs baseline: 1.2084x; 1.1265x over previous
//
#include <hip/hip_runtime.h>

#define HIDDEN 512
#define HEADS 8
#define DK 64
#define S_ 1024
#define NEGV -1000000000.0f

typedef _Float16 half8 __attribute__((ext_vector_type(8)));
typedef _Float16 half4 __attribute__((ext_vector_type(4)));
typedef _Float16 half2_t __attribute__((ext_vector_type(2)));
typedef float f32x4 __attribute__((ext_vector_type(4)));
typedef float f32x2 __attribute__((ext_vector_type(2)));
typedef int i32x4 __attribute__((ext_vector_type(4)));

// async global->LDS, 16B per lane: LDS dest = uniform base + lane*16 (linear);
// global src is PER-LANE (we use that for the gather + bank-deswizzle).
__device__ __forceinline__ void gload16(const void* g, void* l) {
  __builtin_amdgcn_global_load_lds(
      (const __attribute__((address_space(1))) unsigned int*)g,
      (__attribute__((address_space(3))) unsigned int*)l, 16, 0, 0);
}

// ---------------- fp32 -> fp16 converters ----------------
__global__ __launch_bounds__(256) void cvt3(const float* __restrict__ a0,
                                            const float* __restrict__ a1,
                                            const float* __restrict__ a2,
                                            _Float16* o0, _Float16* o1, _Float16* o2) {
  const float* src = blockIdx.y == 0 ? a0 : (blockIdx.y == 1 ? a1 : a2);
  _Float16* dst = blockIdx.y == 0 ? o0 : (blockIdx.y == 1 ? o1 : o2);
  int i = (blockIdx.x * 256 + threadIdx.x) * 4;
  float4 v = *(const float4*)(src + i);
  half4 h = {(_Float16)v.x, (_Float16)v.y, (_Float16)v.z, (_Float16)v.w};
  *(half4*)(dst + i) = h;
}

__global__ __launch_bounds__(256) void cvt4(const float* __restrict__ a0,
                                            const float* __restrict__ a1,
                                            const float* __restrict__ a2,
                                            const float* __restrict__ a3,
                                            _Float16* o0, _Float16* o1, _Float16* o2, _Float16* o3) {
  const float* src = blockIdx.y == 0 ? a0 : (blockIdx.y == 1 ? a1 : (blockIdx.y == 2 ? a2 : a3));
  _Float16* dst = blockIdx.y == 0 ? o0 : (blockIdx.y == 1 ? o1 : (blockIdx.y == 2 ? o2 : o3));
  int i = (blockIdx.x * 256 + threadIdx.x) * 4;
  float4 v = *(const float4*)(src + i);
  half4 h = {(_Float16)v.x, (_Float16)v.y, (_Float16)v.z, (_Float16)v.w};
  *(half4*)(dst + i) = h;
}

// ---------------- fuse gmask+subsq -> fp16 ----------------
__global__ __launch_bounds__(256) void fusemask(const int* __restrict__ gm,
                                                const float* __restrict__ sq,
                                                _Float16* __restrict__ msk) {
  int i = (blockIdx.x * 256 + threadIdx.x) * 4;
  i32x4 g = *(const i32x4*)(gm + i);
  f32x4 s = *(const f32x4*)(sq + i);
  half4 o;
#pragma unroll
  for (int j = 0; j < 4; j++)
    o[j] = (_Float16)(g[j] == 0 ? -30000.0f : s[j]);
  *(half4*)(msk + i) = o;
}

// ---------------- fused QKV projection ----------------
__global__ __launch_bounds__(256) void proj_qkv(
    const _Float16* __restrict__ q16, const _Float16* __restrict__ k16,
    const _Float16* __restrict__ v16,
    const _Float16* __restrict__ wq, const _Float16* __restrict__ wk,
    const _Float16* __restrict__ wv,
    const float* __restrict__ bq, const float* __restrict__ bk,
    const float* __restrict__ bv,
    _Float16* __restrict__ qh, _Float16* __restrict__ kh, _Float16* __restrict__ vt) {
  int m0 = blockIdx.x * 64;
  int nb = blockIdx.y;
  int which = nb >> 3;
  int n0 = (nb & 7) * 64;
  const _Float16* X = which == 0 ? q16 : (which == 1 ? k16 : v16);
  const _Float16* W = which == 0 ? wq : (which == 1 ? wk : wv);
  const float* bias = which == 0 ? bq : (which == 1 ? bk : bv);

  int tid = threadIdx.x;
  int wave = tid >> 6, lane = tid & 63;
  int r16 = lane & 15, quad = lane >> 4;

  const _Float16* Xp = X + (m0 + wave * 16 + r16) * HIDDEN + quad * 8;
  const _Float16* Wp = W + (n0 + r16) * HIDDEN + quad * 8;

  f32x4 acc[4] = {};
  for (int k0 = 0; k0 < HIDDEN; k0 += 32) {
    half8 a = *(const half8*)(Xp + k0);
#pragma unroll
    for (int nt = 0; nt < 4; nt++) {
      half8 bfr = *(const half8*)(Wp + nt * 16 * HIDDEN + k0);
      acc[nt] = __builtin_amdgcn_mfma_f32_16x16x32_f16(a, bfr, acc[nt], 0, 0, 0);
    }
  }

  __shared__ _Float16 T[64][72];

  if (which < 2) {
    _Float16* OUT = which == 0 ? qh : kh;
    float scale = which == 0 ? 0.125f : 1.0f;
#pragma unroll
    for (int nt = 0; nt < 4; nt++) {
      int gcol = n0 + nt * 16 + r16;
      float bv_ = bias[gcol];
      int h = gcol >> 6, d = gcol & 63;
#pragma unroll
      for (int r = 0; r < 4; r++) {
        int grow = m0 + wave * 16 + quad * 4 + r;
        int bb = grow >> 10, s = grow & 1023;
        float val = (acc[nt][r] + bv_) * scale;
        OUT[((bb * HEADS + h) * S_ + s) * DK + d] = (_Float16)val;
      }
    }
  } else {
#pragma unroll
    for (int nt = 0; nt < 4; nt++) {
      int lc = nt * 16 + r16;
      float bv_ = bias[n0 + lc];
#pragma unroll
      for (int r = 0; r < 4; r++) {
        int lr = wave * 16 + quad * 4 + r;
        T[lr][lc] = (_Float16)(acc[nt][r] + bv_);
      }
    }
    __syncthreads();
    int dl = tid >> 2;
    int s4 = (tid & 3) * 16;
    _Float16 tmp[16];
#pragma unroll
    for (int i = 0; i < 16; i++) tmp[i] = T[s4 + i][dl];
    int h = n0 >> 6;
    int bb = m0 >> 10;
    int s0 = m0 & 1023;
    _Float16* p = vt + ((bb * HEADS + h) * DK + dl) * S_ + s0 + s4;
    *(half8*)(p) = *(half8*)(tmp);
    *(half8*)(p + 8) = *(half8*)(tmp + 8);
  }
}

// ---------------- attention v7: global_load_lds-staged bias/msk ----------------
// grid (S/64, B*H); 8 waves; waves 0-3 kv [0,512), 4-7 [512,1024).
// Per wave, per 64-k tile: 6 gload_lds (bias 4KB + msk 2KB, XOR-pre-swizzled
// source gather), ONE vmcnt(0), then 2x 32-k MFMA bodies reading LDS.
// Per-wave private buffers -> no barriers in the loop.
__global__ __launch_bounds__(512) void attn7(
    const _Float16* __restrict__ qh, const _Float16* __restrict__ kh,
    const _Float16* __restrict__ vt,
    const float* __restrict__ attn_bias, const _Float16* __restrict__ msk,
    _Float16* __restrict__ ao) {
  int bh = blockIdx.y;
  int b = bh >> 3, h = bh & 7;
  int tid = threadIdx.x;
  int wave = tid >> 6, lane = tid & 63;
  int col = lane & 15, quad = lane >> 4;
  int qw = wave & 3, zz = wave >> 2;
  int q0w = blockIdx.x * 64 + qw * 16;
  int q = q0w + col;

  // SMEM: [0,32768) bias stage (8 waves x 4KB) | [32768,49152) msk stage
  //       (8 x 2KB) | [49152,59392) P2.  CACC/CML overlay bias after loop.
  __shared__ __align__(16) char SMEM[59392];
  char* bws = SMEM + wave * 4096;
  char* mws = SMEM + 32768 + wave * 2048;
  float* Bw = (float*)bws;
  _Float16* Mw = (_Float16*)mws;
  unsigned(*P2)[16][20] = (unsigned(*)[16][20])(SMEM + 49152);
  float(*CACC)[16][66] = (float(*)[16][66])SMEM;
  float(*CML)[16][2] = (float(*)[16][2])(SMEM + 16896);

  const _Float16* Q = qh + ((size_t)bh * S_ + q) * DK;
  const _Float16* K = kh + (size_t)bh * S_ * DK;
  const _Float16* V = vt + (size_t)bh * DK * S_;
  const float* BIrow = attn_bias + ((size_t)bh * S_ + q0w) * S_;
  const _Float16* MSrow = msk + ((size_t)b * S_ + q0w) * S_;

  half8 qf0 = *(const half8*)(Q + quad * 8);
  half8 qf1 = *(const half8*)(Q + 32 + quad * 8);

  f32x4 acc[4] = {};  // out^T: acc[nt][r] = out[d = nt*16+quad*4+r][q]
  float m_r = -1e38f, l_r = 0.0f;
  int xr = col & 7;

  int kv0 = zz * 512;

  for (int t = 0; t < 8; t++) {
    int kb = kv0 + t * 64;
    // ---- stage: bias 4x1KB (4 rows each), msk 2x1KB (8 rows each) ----
    // source unit pre-swizzled: logical unit j stored at physical j^(row&7)
#pragma unroll
    for (int c = 0; c < 4; c++) {
      int row = c * 4 + (lane >> 4);
      int ju = (lane & 15) ^ (row & 7);
      gload16(BIrow + (size_t)row * S_ + kb + ju * 4, bws + c * 1024);
    }
#pragma unroll
    for (int c = 0; c < 2; c++) {
      int row = c * 8 + (lane >> 3);
      int ju = (lane & 7) ^ (row & 7);
      gload16(MSrow + (size_t)row * S_ + kb + ju * 8, mws + c * 1024);
    }
    asm volatile("s_waitcnt vmcnt(0)" ::: "memory");
    __builtin_amdgcn_sched_barrier(0);

    // ---- two 32-k bodies ----
#pragma unroll
    for (int half = 0; half < 2; half++) {
      int kcl = half * 32;
      int kc = kb + kcl;

      const _Float16* Kp0 = K + (size_t)(kc + col) * DK + quad * 8;
      const _Float16* Kp1 = K + (size_t)(kc + 16 + col) * DK + quad * 8;
      half8 kf00 = *(const half8*)(Kp0);
      half8 kf01 = *(const half8*)(Kp0 + 32);
      half8 kf10 = *(const half8*)(Kp1);
      half8 kf11 = *(const half8*)(Kp1 + 32);

      const _Float16* Vb = V + kc + quad * 8;
      half8 vf0 = *(const half8*)(Vb + (0 * 16 + col) * S_);
      half8 vf1 = *(const half8*)(Vb + (1 * 16 + col) * S_);
      half8 vf2 = *(const half8*)(Vb + (2 * 16 + col) * S_);
      half8 vf3 = *(const half8*)(Vb + (3 * 16 + col) * S_);

      // LDS reads (inverse swizzle applied)
      int jb = kcl >> 2;  // 0 or 8
      f32x4 bi0 = *(const f32x4*)&Bw[col * 64 + (((jb + quad) ^ xr) << 2)];
      f32x4 bi1 = *(const f32x4*)&Bw[col * 64 + (((jb + 4 + quad) ^ xr) << 2)];
      int jm = (kcl >> 3) + (quad >> 1);  // 0|4 (+0|1)
      half4 mk0 = *(const half4*)&Mw[col * 64 + ((jm ^ xr) << 3) + (quad & 1) * 4];
      half4 mk1 = *(const half4*)&Mw[col * 64 + (((jm + 2) ^ xr) << 3) + (quad & 1) * 4];

      // QK^T swapped: S^T[k][q]
      f32x4 s0 = {}, s1 = {};
      s0 = __builtin_amdgcn_mfma_f32_16x16x32_f16(kf00, qf0, s0, 0, 0, 0);
      s0 = __builtin_amdgcn_mfma_f32_16x16x32_f16(kf01, qf1, s0, 0, 0, 0);
      s1 = __builtin_amdgcn_mfma_f32_16x16x32_f16(kf10, qf0, s1, 0, 0, 0);
      s1 = __builtin_amdgcn_mfma_f32_16x16x32_f16(kf11, qf1, s1, 0, 0, 0);

      float x0[4], x1[4];
#pragma unroll
      for (int r = 0; r < 4; r++) {
        x0[r] = s0[r] + bi0[r] + (float)mk0[r];
        x1[r] = s1[r] + bi1[r] + (float)mk1[r];
      }

      float mx = fmaxf(fmaxf(fmaxf(x0[0], x0[1]), fmaxf(x0[2], x0[3])),
                       fmaxf(fmaxf(x1[0], x1[1]), fmaxf(x1[2], x1[3])));
      mx = fmaxf(mx, __shfl_xor(mx, 16));
      mx = fmaxf(mx, __shfl_xor(mx, 32));
      float mnew = fmaxf(m_r, mx);
      float f = __expf(m_r - mnew);
      float p0[4], p1[4];
      float ps = 0.0f;
#pragma unroll
      for (int r = 0; r < 4; r++) {
        p0[r] = __expf(x0[r] - mnew);
        p1[r] = __expf(x1[r] - mnew);
        ps += p0[r] + p1[r];
      }
      ps += __shfl_xor(ps, 16);
      ps += __shfl_xor(ps, 32);
      l_r = l_r * f + ps;
      m_r = mnew;
#pragma unroll
      for (int nt = 0; nt < 4; nt++) acc[nt] *= f;

      half2_t c0 = {(_Float16)p0[0], (_Float16)p0[1]};
      half2_t c1 = {(_Float16)p0[2], (_Float16)p0[3]};
      half2_t c2 = {(_Float16)p1[0], (_Float16)p1[1]};
      half2_t c3 = {(_Float16)p1[2], (_Float16)p1[3]};
      P2[wave][col][quad * 2 + 0] = __builtin_bit_cast(unsigned, c0);
      P2[wave][col][quad * 2 + 1] = __builtin_bit_cast(unsigned, c1);
      P2[wave][col][8 + quad * 2 + 0] = __builtin_bit_cast(unsigned, c2);
      P2[wave][col][8 + quad * 2 + 1] = __builtin_bit_cast(unsigned, c3);

      half8 pf = *(const half8*)&P2[wave][col][quad * 4];

      acc[0] = __builtin_amdgcn_mfma_f32_16x16x32_f16(vf0, pf, acc[0], 0, 0, 0);
      acc[1] = __builtin_amdgcn_mfma_f32_16x16x32_f16(vf1, pf, acc[1], 0, 0, 0);
      acc[2] = __builtin_amdgcn_mfma_f32_16x16x32_f16(vf2, pf, acc[2], 0, 0, 0);
      acc[3] = __builtin_amdgcn_mfma_f32_16x16x32_f16(vf3, pf, acc[3], 0, 0, 0);
    }
  }

  // --- merge the two kv halves (CACC overlays staging; sync first) ---
  __syncthreads();
  if (zz == 1) {
#pragma unroll
    for (int nt = 0; nt < 4; nt++)
#pragma unroll
      for (int rp = 0; rp < 2; rp++) {
        int d = nt * 16 + quad * 4 + rp * 2;
        f32x2 v2 = {acc[nt][rp * 2], acc[nt][rp * 2 + 1]};
        *(f32x2*)&CACC[qw][col][d] = v2;
      }
    if (quad == 0) {
      CML[qw][col][0] = m_r;
      CML[qw][col][1] = l_r;
    }
  }
  __syncthreads();
  if (zz == 0) {
    float m1 = CML[qw][col][0], l1 = CML[qw][col][1];
    float mm = fmaxf(m_r, m1);
    float e0 = __expf(m_r - mm), e1 = __expf(m1 - mm);
    float linv = 1.0f / (l_r * e0 + l1 * e1);
    _Float16* aop = ao + (size_t)(b * S_ + q) * HIDDEN + h * DK;
#pragma unroll
    for (int nt = 0; nt < 4; nt++)
#pragma unroll
      for (int rp = 0; rp < 2; rp++) {
        int d = nt * 16 + quad * 4 + rp * 2;
        f32x2 a1 = *(const f32x2*)&CACC[qw][col][d];
        float o0 = (acc[nt][rp * 2] * e0 + a1[0] * e1) * linv;
        float o1 = (acc[nt][rp * 2 + 1] * e0 + a1[1] * e1) * linv;
        half2_t o = {(_Float16)o0, (_Float16)o1};
        *(half2_t*)(aop + d) = o;
      }
  }
}

// ---------------- output projection ----------------
__global__ __launch_bounds__(256) void out_proj(
    const _Float16* __restrict__ ao, const _Float16* __restrict__ wo,
    const float* __restrict__ bo, float* __restrict__ out) {
  int m0 = blockIdx.x * 64;
  int n0 = blockIdx.y * 64;
  int tid = threadIdx.x, wave = tid >> 6, lane = tid & 63;
  int r16 = lane & 15, quad = lane >> 4;
  const _Float16* Ap = ao + (m0 + wave * 16 + r16) * HIDDEN + quad * 8;
  const _Float16* Wp = wo + (n0 + r16) * HIDDEN + quad * 8;
  f32x4 acc[4] = {};
  for (int k0 = 0; k0 < HIDDEN; k0 += 32) {
    half8 a = *(const half8*)(Ap + k0);
#pragma unroll
    for (int nt = 0; nt < 4; nt++) {
      half8 bfr = *(const half8*)(Wp + nt * 16 * HIDDEN + k0);
      acc[nt] = __builtin_amdgcn_mfma_f32_16x16x32_f16(a, bfr, acc[nt], 0, 0, 0);
    }
  }
#pragma unroll
  for (int nt = 0; nt < 4; nt++) {
    int gcol = n0 + nt * 16 + r16;
    float bv_ = bo[gcol];
#pragma unroll
    for (int r = 0; r < 4; r++) {
      int grow = m0 + wave * 16 + quad * 4 + r;
      out[grow * HIDDEN + gcol] = acc[nt][r] + bv_;
    }
  }
}

// ---------------- launch ----------------
extern "C" void kernel_launch(void* const* d_in, const int* in_sizes, int n_in,
                              void* d_out, int out_size, void* d_ws, size_t ws_size,
                              hipStream_t stream) {
  const float* q = (const float*)d_in[0];
  const float* k = (const float*)d_in[1];
  const float* v = (const float*)d_in[2];
  const float* attn_bias = (const float*)d_in[3];
  const int* gmask = (const int*)d_in[4];
  const float* subsq = (const float*)d_in[5];
  const float* Wq = (const float*)d_in[6];
  const float* bq = (const float*)d_in[7];
  const float* Wk = (const float*)d_in[8];
  const float* bk = (const float*)d_in[9];
  const float* Wv = (const float*)d_in[10];
  const float* bv = (const float*)d_in[11];
  const float* Wo = (const float*)d_in[12];
  const float* bo = (const float*)d_in[13];

  char* ws = (char*)d_ws;
  _Float16* q16 = (_Float16*)(ws + 0);
  _Float16* k16 = (_Float16*)(ws + 4194304);
  _Float16* v16 = (_Float16*)(ws + 8388608);
  _Float16* wq16 = (_Float16*)(ws + 12582912);
  _Float16* wk16 = (_Float16*)(ws + 13107200);
  _Float16* wv16 = (_Float16*)(ws + 13631488);
  _Float16* wo16 = (_Float16*)(ws + 14155776);
  _Float16* qhb = (_Float16*)(ws + 14680064);
  _Float16* khb = (_Float16*)(ws + 18874368);
  _Float16* vtb = (_Float16*)(ws + 23068672);
  _Float16* aob = (_Float16*)(ws + 27262976);
  // msk16 overlays q16/k16 region (8 MB, dead after proj_qkv)
  _Float16* msk16 = (_Float16*)(ws + 0);

  cvt3<<<dim3(2048, 3), 256, 0, stream>>>(q, k, v, q16, k16, v16);
  cvt4<<<dim3(256, 4), 256, 0, stream>>>(Wq, Wk, Wv, Wo, wq16, wk16, wv16, wo16);
  proj_qkv<<<dim3(64, 24), 256, 0, stream>>>(q16, k16, v16, wq16, wk16, wv16,
                                             bq, bk, bv, qhb, khb, vtb);
  fusemask<<<dim3(4096), 256, 0, stream>>>(gmask, subsq, msk16);
  attn7<<<dim3(16, 32), 512, 0, stream>>>(qhb, khb, vtb, attn_bias, msk16, aob);
  out_proj<<<dim3(64, 8), 256, 0, stream>>>(aob, wo16, bo, (float*)d_out);
}

// Round 8
// 138.087 us; speedup vs baseline: 1.4533x; 1.2026x over previous
//
#include <hip/hip_runtime.h>

#define HIDDEN 512
#define HEADS 8
#define DK 64
#define S_ 1024
#define NEGV -1000000000.0f

typedef _Float16 half8 __attribute__((ext_vector_type(8)));
typedef _Float16 half4 __attribute__((ext_vector_type(4)));
typedef _Float16 half2_t __attribute__((ext_vector_type(2)));
typedef float f32x4 __attribute__((ext_vector_type(4)));
typedef float f32x2 __attribute__((ext_vector_type(2)));
typedef int i32x4 __attribute__((ext_vector_type(4)));

// async global->LDS, 16B/lane: LDS dest = uniform base + lane*16 (linear);
// global src is per-lane (used for gather + bank-deswizzle).
__device__ __forceinline__ void gload16(const void* g, void* l) {
  __builtin_amdgcn_global_load_lds(
      (const __attribute__((address_space(1))) unsigned int*)g,
      (__attribute__((address_space(3))) unsigned int*)l, 16, 0, 0);
}

// ---------------- fp32 -> fp16 converters ----------------
__global__ __launch_bounds__(256) void cvt3(const float* __restrict__ a0,
                                            const float* __restrict__ a1,
                                            const float* __restrict__ a2,
                                            _Float16* o0, _Float16* o1, _Float16* o2) {
  const float* src = blockIdx.y == 0 ? a0 : (blockIdx.y == 1 ? a1 : a2);
  _Float16* dst = blockIdx.y == 0 ? o0 : (blockIdx.y == 1 ? o1 : o2);
  int i = (blockIdx.x * 256 + threadIdx.x) * 4;
  float4 v = *(const float4*)(src + i);
  half4 h = {(_Float16)v.x, (_Float16)v.y, (_Float16)v.z, (_Float16)v.w};
  *(half4*)(dst + i) = h;
}

__global__ __launch_bounds__(256) void cvt4(const float* __restrict__ a0,
                                            const float* __restrict__ a1,
                                            const float* __restrict__ a2,
                                            const float* __restrict__ a3,
                                            _Float16* o0, _Float16* o1, _Float16* o2, _Float16* o3) {
  const float* src = blockIdx.y == 0 ? a0 : (blockIdx.y == 1 ? a1 : (blockIdx.y == 2 ? a2 : a3));
  _Float16* dst = blockIdx.y == 0 ? o0 : (blockIdx.y == 1 ? o1 : (blockIdx.y == 2 ? o2 : o3));
  int i = (blockIdx.x * 256 + threadIdx.x) * 4;
  float4 v = *(const float4*)(src + i);
  half4 h = {(_Float16)v.x, (_Float16)v.y, (_Float16)v.z, (_Float16)v.w};
  *(half4*)(dst + i) = h;
}

// ---------------- fuse gmask+subsq -> fp16 ----------------
__global__ __launch_bounds__(256) void fusemask(const int* __restrict__ gm,
                                                const float* __restrict__ sq,
                                                _Float16* __restrict__ msk) {
  int i = (blockIdx.x * 256 + threadIdx.x) * 4;
  i32x4 g = *(const i32x4*)(gm + i);
  f32x4 s = *(const f32x4*)(sq + i);
  half4 o;
#pragma unroll
  for (int j = 0; j < 4; j++)
    o[j] = (_Float16)(g[j] == 0 ? -30000.0f : s[j]);
  *(half4*)(msk + i) = o;
}

// ---------------- fused QKV projection ----------------
__global__ __launch_bounds__(256) void proj_qkv(
    const _Float16* __restrict__ q16, const _Float16* __restrict__ k16,
    const _Float16* __restrict__ v16,
    const _Float16* __restrict__ wq, const _Float16* __restrict__ wk,
    const _Float16* __restrict__ wv,
    const float* __restrict__ bq, const float* __restrict__ bk,
    const float* __restrict__ bv,
    _Float16* __restrict__ qh, _Float16* __restrict__ kh, _Float16* __restrict__ vt) {
  int m0 = blockIdx.x * 64;
  int nb = blockIdx.y;
  int which = nb >> 3;
  int n0 = (nb & 7) * 64;
  const _Float16* X = which == 0 ? q16 : (which == 1 ? k16 : v16);
  const _Float16* W = which == 0 ? wq : (which == 1 ? wk : wv);
  const float* bias = which == 0 ? bq : (which == 1 ? bk : bv);

  int tid = threadIdx.x;
  int wave = tid >> 6, lane = tid & 63;
  int r16 = lane & 15, quad = lane >> 4;

  const _Float16* Xp = X + (m0 + wave * 16 + r16) * HIDDEN + quad * 8;
  const _Float16* Wp = W + (n0 + r16) * HIDDEN + quad * 8;

  f32x4 acc[4] = {};
  for (int k0 = 0; k0 < HIDDEN; k0 += 32) {
    half8 a = *(const half8*)(Xp + k0);
#pragma unroll
    for (int nt = 0; nt < 4; nt++) {
      half8 bfr = *(const half8*)(Wp + nt * 16 * HIDDEN + k0);
      acc[nt] = __builtin_amdgcn_mfma_f32_16x16x32_f16(a, bfr, acc[nt], 0, 0, 0);
    }
  }

  __shared__ _Float16 T[64][72];

  if (which < 2) {
    _Float16* OUT = which == 0 ? qh : kh;
    float scale = which == 0 ? 0.125f : 1.0f;
#pragma unroll
    for (int nt = 0; nt < 4; nt++) {
      int gcol = n0 + nt * 16 + r16;
      float bv_ = bias[gcol];
      int h = gcol >> 6, d = gcol & 63;
#pragma unroll
      for (int r = 0; r < 4; r++) {
        int grow = m0 + wave * 16 + quad * 4 + r;
        int bb = grow >> 10, s = grow & 1023;
        float val = (acc[nt][r] + bv_) * scale;
        OUT[((bb * HEADS + h) * S_ + s) * DK + d] = (_Float16)val;
      }
    }
  } else {
#pragma unroll
    for (int nt = 0; nt < 4; nt++) {
      int lc = nt * 16 + r16;
      float bv_ = bias[n0 + lc];
#pragma unroll
      for (int r = 0; r < 4; r++) {
        int lr = wave * 16 + quad * 4 + r;
        T[lr][lc] = (_Float16)(acc[nt][r] + bv_);
      }
    }
    __syncthreads();
    int dl = tid >> 2;
    int s4 = (tid & 3) * 16;
    _Float16 tmp[16];
#pragma unroll
    for (int i = 0; i < 16; i++) tmp[i] = T[s4 + i][dl];
    int h = n0 >> 6;
    int bb = m0 >> 10;
    int s0 = m0 & 1023;
    _Float16* p = vt + ((bb * HEADS + h) * DK + dl) * S_ + s0 + s4;
    *(half8*)(p) = *(half8*)(tmp);
    *(half8*)(p + 8) = *(half8*)(tmp + 8);
  }
}

// ---------------- attention v8: fully-LDS-staged tiles, XCD-local K/V ----------------
// grid 512 x 256 threads (4 waves). Block handles 64 q-rows x full kv.
// XCD swizzle: bh & 7 == xcd so each XCD's K/V = 4 bh x 256 KB = 1 MB (L2-fit).
// Per 64-k tile: 4 waves issue 40 gload16 total (K 8, V 8, bias 16, msk 8;
// XOR-pre-swizzled sources), ONE vmcnt(0)+barrier, two all-LDS MFMA bodies.
__global__ __launch_bounds__(256) void attn8(
    const _Float16* __restrict__ qh, const _Float16* __restrict__ kh,
    const _Float16* __restrict__ vt,
    const float* __restrict__ attn_bias, const _Float16* __restrict__ msk,
    _Float16* __restrict__ ao) {
  int id = blockIdx.x;
  int bh = (((id >> 3) & 3) << 3) | (id & 7);  // bh&7 == dispatch xcd (id&7)
  int qtile = id >> 5;
  int b = bh >> 3, h = bh & 7;
  int tid = threadIdx.x;
  int wave = tid >> 6, lane = tid & 63;
  int col = lane & 15, quad = lane >> 4;
  int q0w = qtile * 64 + wave * 16;
  int q = q0w + col;
  int xr = col & 7;
  int lr8 = lane >> 3;
  int u8 = (lane & 7) ^ lr8;  // xor-pre-swizzled 16B unit for 8-row gloads

  // LDS: K 8KB | V 8KB | bias 4x4KB | msk 4x2KB | P2 5KB = 45KB
  __shared__ __align__(16) char SMEM[46080];
  _Float16* Klds = (_Float16*)SMEM;            // [64 k-rows][64 d]
  _Float16* Vlds = (_Float16*)(SMEM + 8192);   // [64 d-rows][64 k]
  char* bws = SMEM + 16384 + wave * 4096;
  char* mws = SMEM + 32768 + wave * 2048;
  float* Bw = (float*)bws;
  _Float16* Mw = (_Float16*)mws;
  unsigned(*P2)[16][20] = (unsigned(*)[16][20])(SMEM + 40960);

  const _Float16* Q = qh + ((size_t)bh * S_ + q) * DK;
  const _Float16* K = kh + (size_t)bh * S_ * DK;
  const _Float16* V = vt + (size_t)bh * DK * S_;
  const float* BIrow = attn_bias + ((size_t)bh * S_ + q0w) * S_;
  const _Float16* MSrow = msk + ((size_t)b * S_ + q0w) * S_;

  half8 qf0 = *(const half8*)(Q + quad * 8);
  half8 qf1 = *(const half8*)(Q + 32 + quad * 8);

  f32x4 acc[4] = {};  // out^T: acc[nt][r] = out[d = nt*16+quad*4+r][q]
  float m_r = -1e38f, l_r = 0.0f;

  for (int t = 0; t < 16; t++) {
    int kb = t * 64;
    // ---- stage (shared K/V split across waves; own bias/msk) ----
#pragma unroll
    for (int cc = 0; cc < 2; cc++) {
      int c = wave + cc * 4;             // 0..7
      int row = c * 8 + lr8;             // k-local row 0..63 (row&7 == lr8)
      gload16(K + (size_t)(kb + row) * DK + u8 * 8, SMEM + c * 1024);
    }
#pragma unroll
    for (int cc = 0; cc < 2; cc++) {
      int c = wave + cc * 4;
      int row = c * 8 + lr8;             // d-row 0..63
      gload16(V + (size_t)row * S_ + kb + u8 * 8, SMEM + 8192 + c * 1024);
    }
#pragma unroll
    for (int c = 0; c < 4; c++) {
      int row = c * 4 + (lane >> 4);     // q-local row 0..15
      int ju = (lane & 15) ^ (row & 7);
      gload16(BIrow + (size_t)row * S_ + kb + ju * 4, bws + c * 1024);
    }
#pragma unroll
    for (int c = 0; c < 2; c++) {
      int row = c * 8 + lr8;             // q-local row 0..15 (row&7 == lr8)
      gload16(MSrow + (size_t)row * S_ + kb + u8 * 8, mws + c * 1024);
    }
    asm volatile("s_waitcnt vmcnt(0)" ::: "memory");
    __builtin_amdgcn_sched_barrier(0);
    __builtin_amdgcn_s_barrier();

    // ---- two 32-k bodies, all operands from LDS ----
#pragma unroll
    for (int hf = 0; hf < 2; hf++) {
      int kcl = hf * 32;
      int R0 = kcl + col, R1 = kcl + 16 + col;
      half8 kf00 = *(const half8*)&Klds[R0 * 64 + ((quad ^ xr) << 3)];
      half8 kf01 = *(const half8*)&Klds[R0 * 64 + (((quad + 4) ^ xr) << 3)];
      half8 kf10 = *(const half8*)&Klds[R1 * 64 + ((quad ^ xr) << 3)];
      half8 kf11 = *(const half8*)&Klds[R1 * 64 + (((quad + 4) ^ xr) << 3)];

      int ku = (kcl >> 3) + quad;  // logical 8-elem k-unit
      half8 vf0 = *(const half8*)&Vlds[(0 * 16 + col) * 64 + ((ku ^ xr) << 3)];
      half8 vf1 = *(const half8*)&Vlds[(1 * 16 + col) * 64 + ((ku ^ xr) << 3)];
      half8 vf2 = *(const half8*)&Vlds[(2 * 16 + col) * 64 + ((ku ^ xr) << 3)];
      half8 vf3 = *(const half8*)&Vlds[(3 * 16 + col) * 64 + ((ku ^ xr) << 3)];

      int jb = kcl >> 2;  // 0 or 8
      f32x4 bi0 = *(const f32x4*)&Bw[col * 64 + (((jb + quad) ^ xr) << 2)];
      f32x4 bi1 = *(const f32x4*)&Bw[col * 64 + (((jb + 4 + quad) ^ xr) << 2)];
      int jm = (kcl >> 3) + (quad >> 1);
      half4 mk0 = *(const half4*)&Mw[col * 64 + ((jm ^ xr) << 3) + (quad & 1) * 4];
      half4 mk1 = *(const half4*)&Mw[col * 64 + (((jm + 2) ^ xr) << 3) + (quad & 1) * 4];

      // QK^T swapped: S^T[k][q]
      f32x4 s0 = {}, s1 = {};
      s0 = __builtin_amdgcn_mfma_f32_16x16x32_f16(kf00, qf0, s0, 0, 0, 0);
      s0 = __builtin_amdgcn_mfma_f32_16x16x32_f16(kf01, qf1, s0, 0, 0, 0);
      s1 = __builtin_amdgcn_mfma_f32_16x16x32_f16(kf10, qf0, s1, 0, 0, 0);
      s1 = __builtin_amdgcn_mfma_f32_16x16x32_f16(kf11, qf1, s1, 0, 0, 0);

      float x0[4], x1[4];
#pragma unroll
      for (int r = 0; r < 4; r++) {
        x0[r] = s0[r] + bi0[r] + (float)mk0[r];
        x1[r] = s1[r] + bi1[r] + (float)mk1[r];
      }

      float mx = fmaxf(fmaxf(fmaxf(x0[0], x0[1]), fmaxf(x0[2], x0[3])),
                       fmaxf(fmaxf(x1[0], x1[1]), fmaxf(x1[2], x1[3])));
      mx = fmaxf(mx, __shfl_xor(mx, 16));
      mx = fmaxf(mx, __shfl_xor(mx, 32));
      float mnew = fmaxf(m_r, mx);
      float f = __expf(m_r - mnew);
      float p0[4], p1[4];
      float ps = 0.0f;
#pragma unroll
      for (int r = 0; r < 4; r++) {
        p0[r] = __expf(x0[r] - mnew);
        p1[r] = __expf(x1[r] - mnew);
        ps += p0[r] + p1[r];
      }
      ps += __shfl_xor(ps, 16);
      ps += __shfl_xor(ps, 32);
      l_r = l_r * f + ps;
      m_r = mnew;
#pragma unroll
      for (int nt = 0; nt < 4; nt++) acc[nt] *= f;

      half2_t c0 = {(_Float16)p0[0], (_Float16)p0[1]};
      half2_t c1 = {(_Float16)p0[2], (_Float16)p0[3]};
      half2_t c2 = {(_Float16)p1[0], (_Float16)p1[1]};
      half2_t c3 = {(_Float16)p1[2], (_Float16)p1[3]};
      P2[wave][col][quad * 2 + 0] = __builtin_bit_cast(unsigned, c0);
      P2[wave][col][quad * 2 + 1] = __builtin_bit_cast(unsigned, c1);
      P2[wave][col][8 + quad * 2 + 0] = __builtin_bit_cast(unsigned, c2);
      P2[wave][col][8 + quad * 2 + 1] = __builtin_bit_cast(unsigned, c3);

      half8 pf = *(const half8*)&P2[wave][col][quad * 4];

      acc[0] = __builtin_amdgcn_mfma_f32_16x16x32_f16(vf0, pf, acc[0], 0, 0, 0);
      acc[1] = __builtin_amdgcn_mfma_f32_16x16x32_f16(vf1, pf, acc[1], 0, 0, 0);
      acc[2] = __builtin_amdgcn_mfma_f32_16x16x32_f16(vf2, pf, acc[2], 0, 0, 0);
      acc[3] = __builtin_amdgcn_mfma_f32_16x16x32_f16(vf3, pf, acc[3], 0, 0, 0);
    }
    __builtin_amdgcn_s_barrier();  // protect K/V/stage buffers from next tile
  }

  // ---- epilogue: normalize and write ----
  float linv = 1.0f / l_r;
  _Float16* aop = ao + (size_t)(b * S_ + q) * HIDDEN + h * DK;
#pragma unroll
  for (int nt = 0; nt < 4; nt++)
#pragma unroll
    for (int rp = 0; rp < 2; rp++) {
      int d = nt * 16 + quad * 4 + rp * 2;
      half2_t o = {(_Float16)(acc[nt][rp * 2] * linv),
                   (_Float16)(acc[nt][rp * 2 + 1] * linv)};
      *(half2_t*)(aop + d) = o;
    }
}

// ---------------- output projection ----------------
__global__ __launch_bounds__(256) void out_proj(
    const _Float16* __restrict__ ao, const _Float16* __restrict__ wo,
    const float* __restrict__ bo, float* __restrict__ out) {
  int m0 = blockIdx.x * 64;
  int n0 = blockIdx.y * 64;
  int tid = threadIdx.x, wave = tid >> 6, lane = tid & 63;
  int r16 = lane & 15, quad = lane >> 4;
  const _Float16* Ap = ao + (m0 + wave * 16 + r16) * HIDDEN + quad * 8;
  const _Float16* Wp = wo + (n0 + r16) * HIDDEN + quad * 8;
  f32x4 acc[4] = {};
  for (int k0 = 0; k0 < HIDDEN; k0 += 32) {
    half8 a = *(const half8*)(Ap + k0);
#pragma unroll
    for (int nt = 0; nt < 4; nt++) {
      half8 bfr = *(const half8*)(Wp + nt * 16 * HIDDEN + k0);
      acc[nt] = __builtin_amdgcn_mfma_f32_16x16x32_f16(a, bfr, acc[nt], 0, 0, 0);
    }
  }
#pragma unroll
  for (int nt = 0; nt < 4; nt++) {
    int gcol = n0 + nt * 16 + r16;
    float bv_ = bo[gcol];
#pragma unroll
    for (int r = 0; r < 4; r++) {
      int grow = m0 + wave * 16 + quad * 4 + r;
      out[grow * HIDDEN + gcol] = acc[nt][r] + bv_;
    }
  }
}

// ---------------- launch ----------------
extern "C" void kernel_launch(void* const* d_in, const int* in_sizes, int n_in,
                              void* d_out, int out_size, void* d_ws, size_t ws_size,
                              hipStream_t stream) {
  const float* q = (const float*)d_in[0];
  const float* k = (const float*)d_in[1];
  const float* v = (const float*)d_in[2];
  const float* attn_bias = (const float*)d_in[3];
  const int* gmask = (const int*)d_in[4];
  const float* subsq = (const float*)d_in[5];
  const float* Wq = (const float*)d_in[6];
  const float* bq = (const float*)d_in[7];
  const float* Wk = (const float*)d_in[8];
  const float* bk = (const float*)d_in[9];
  const float* Wv = (const float*)d_in[10];
  const float* bv = (const float*)d_in[11];
  const float* Wo = (const float*)d_in[12];
  const float* bo = (const float*)d_in[13];

  char* ws = (char*)d_ws;
  _Float16* q16 = (_Float16*)(ws + 0);
  _Float16* k16 = (_Float16*)(ws + 4194304);
  _Float16* v16 = (_Float16*)(ws + 8388608);
  _Float16* wq16 = (_Float16*)(ws + 12582912);
  _Float16* wk16 = (_Float16*)(ws + 13107200);
  _Float16* wv16 = (_Float16*)(ws + 13631488);
  _Float16* wo16 = (_Float16*)(ws + 14155776);
  _Float16* qhb = (_Float16*)(ws + 14680064);
  _Float16* khb = (_Float16*)(ws + 18874368);
  _Float16* vtb = (_Float16*)(ws + 23068672);
  _Float16* aob = (_Float16*)(ws + 27262976);
  // msk16 overlays q16/k16 region (8 MB, dead after proj_qkv)
  _Float16* msk16 = (_Float16*)(ws + 0);

  cvt3<<<dim3(2048, 3), 256, 0, stream>>>(q, k, v, q16, k16, v16);
  cvt4<<<dim3(256, 4), 256, 0, stream>>>(Wq, Wk, Wv, Wo, wq16, wk16, wv16, wo16);
  proj_qkv<<<dim3(64, 24), 256, 0, stream>>>(q16, k16, v16, wq16, wk16, wv16,
                                             bq, bk, bv, qhb, khb, vtb);
  fusemask<<<dim3(4096), 256, 0, stream>>>(gmask, subsq, msk16);
  attn8<<<dim3(512), 256, 0, stream>>>(qhb, khb, vtb, attn_bias, msk16, aob);
  out_proj<<<dim3(64, 8), 256, 0, stream>>>(aob, wo16, bo, (float*)d_out);
}